// Round 2
// baseline (905.483 us; speedup 1.0000x reference)
//
#include <hip/hip_runtime.h>
#include <cmath>

#define TOKENS 16384
#define DM     4096
#define NEXP   64

// ---------------- Kernel A: partial logits via K-split -----------------------
// One thread = one token, 64 expert accumulators in VGPRs.
// wg reads are wave-uniform -> scalar (s_load) pipe; x reads are per-lane
// streaming float4. No LDS at all.
// part[ks][t][e], ks in [0,KSPLIT). Grid = 64 token-blocks * KSPLIT.
template<int KPER>
__global__ __launch_bounds__(256, 2)
void logits_kernel(const float* __restrict__ x, const float* __restrict__ wg,
                   float* __restrict__ part)
{
    constexpr int KSPLIT = DM / KPER;
    const int ks = blockIdx.x & (KSPLIT - 1);
    const int tb = blockIdx.x / KSPLIT;
    const int t  = tb * 256 + threadIdx.x;
    const int k0 = ks * KPER;

    float acc[NEXP];
    #pragma unroll
    for (int e = 0; e < NEXP; ++e) acc[e] = 0.f;

    const float* __restrict__ xrow  = x  + (size_t)t * DM + k0;
    const float* __restrict__ wbase = wg + k0;   // wave-uniform base

    for (int kk = 0; kk < KPER; kk += 4) {
        const float4 xv = *(const float4*)(xrow + kk);
        #pragma unroll
        for (int e = 0; e < NEXP; ++e) {
            // uniform address -> s_load_dwordx4; e*DM*4 + kk*4 fits 21-bit imm
            const float4 wv = *(const float4*)(wbase + (size_t)e * DM + kk);
            acc[e] += xv.x * wv.x + xv.y * wv.y + xv.z * wv.z + xv.w * wv.w;
        }
    }

    float* p = part + ((size_t)ks * TOKENS + t) * NEXP;
    #pragma unroll
    for (int i = 0; i < NEXP / 4; ++i) {
        *(float4*)(p + 4 * i) =
            make_float4(acc[4*i], acc[4*i+1], acc[4*i+2], acc[4*i+3]);
    }
}

// ---------------- Kernel B: reduce partials + softmax + top-2 + partial sums -
// 256 blocks x 256 threads (4 waves). One wave per token (lane = expert),
// 16 tokens per wave. Deterministic fixed-order K-split reduction.
__global__ __launch_bounds__(256)
void gate_kernel(const float* __restrict__ part, float* __restrict__ out,
                 float* __restrict__ p_imp, float* __restrict__ p_cnt,
                 int ksplit)
{
    const int lane = threadIdx.x & 63;
    const int wave = threadIdx.x >> 6;
    const int blk  = blockIdx.x;

    float imp_acc = 0.f;
    float cnt_acc = 0.f;

    for (int i = 0; i < 16; ++i) {
        const int t = blk * 64 + wave * 16 + i;

        float v = 0.f;
        for (int ks = 0; ks < ksplit; ++ks)
            v += part[((size_t)ks * TOKENS + t) * NEXP + lane];

        // softmax over 64 lanes
        float m = v;
        #pragma unroll
        for (int off = 32; off; off >>= 1) m = fmaxf(m, __shfl_xor(m, off));
        const float p = expf(v - m);
        float s = p;
        #pragma unroll
        for (int off = 32; off; off >>= 1) s += __shfl_xor(s, off);
        const float prob = p / s;

        // top-1 (ties -> lower index, matching lax.top_k)
        float bv = prob; int bi = lane;
        #pragma unroll
        for (int off = 32; off; off >>= 1) {
            const float ov = __shfl_xor(bv, off);
            const int   oi = __shfl_xor(bi, off);
            if (ov > bv || (ov == bv && oi < bi)) { bv = ov; bi = oi; }
        }
        // top-2: mask winner, reduce again
        float cv = (lane == bi) ? -1.0f : prob; int ci = lane;
        #pragma unroll
        for (int off = 32; off; off >>= 1) {
            const float ov = __shfl_xor(cv, off);
            const int   oi = __shfl_xor(ci, off);
            if (ov > cv || (ov == cv && oi < ci)) { cv = ov; ci = oi; }
        }

        if (lane == 0) {
            out[2*t]                  = (float)bi;
            out[2*t + 1]              = (float)ci;
            out[2*TOKENS + 2*t]       = bv;
            out[2*TOKENS + 2*t + 1]   = cv;
        }
        imp_acc += prob;
        cnt_acc += (lane == bi) ? 1.0f : 0.0f;
    }

    __shared__ float red[4][NEXP];
    red[wave][lane] = imp_acc;
    __syncthreads();
    if (threadIdx.x < 64) {
        p_imp[blk*NEXP + threadIdx.x] =
            red[0][threadIdx.x] + red[1][threadIdx.x] +
            red[2][threadIdx.x] + red[3][threadIdx.x];
    }
    __syncthreads();
    red[wave][lane] = cnt_acc;
    __syncthreads();
    if (threadIdx.x < 64) {
        p_cnt[blk*NEXP + threadIdx.x] =
            red[0][threadIdx.x] + red[1][threadIdx.x] +
            red[2][threadIdx.x] + red[3][threadIdx.x];
    }
}

// ---------------- Kernel C: aux = E * sum_e importance_e * load_e -----------
__global__ __launch_bounds__(256)
void aux_kernel(const float* __restrict__ p_imp, const float* __restrict__ p_cnt,
                float* __restrict__ out)
{
    __shared__ float s_imp[256];
    __shared__ float s_cnt[256];
    const int tid = threadIdx.x;
    const int e = tid & 63;
    const int c = tid >> 6;           // 4 chunks of 64 blocks
    float si = 0.f, sc = 0.f;
    for (int b = c*64; b < c*64 + 64; ++b) {
        si += p_imp[b*NEXP + e];
        sc += p_cnt[b*NEXP + e];
    }
    s_imp[tid] = si; s_cnt[tid] = sc;
    __syncthreads();
    if (tid < 64) {
        const float imp = s_imp[tid] + s_imp[64+tid] + s_imp[128+tid] + s_imp[192+tid];
        const float cnt = s_cnt[tid] + s_cnt[64+tid] + s_cnt[128+tid] + s_cnt[192+tid];
        float prod = imp * cnt;
        #pragma unroll
        for (int off = 32; off; off >>= 1) prod += __shfl_xor(prod, off);
        if (tid == 0) {
            out[4*TOKENS] = (float)NEXP * prod / ((float)TOKENS * (float)TOKENS);
        }
    }
}

extern "C" void kernel_launch(void* const* d_in, const int* in_sizes, int n_in,
                              void* d_out, int out_size, void* d_ws, size_t ws_size,
                              hipStream_t stream) {
    const float* x  = (const float*)d_in[0];
    const float* wg = (const float*)d_in[1];
    float* out = (float*)d_out;

    // choose K-split by available workspace (partials = KSPLIT * 4 MB)
    const size_t tail = 2 * 256 * NEXP * sizeof(float);
    int ksplit;
    if      (ws_size >= (size_t)8 * TOKENS * NEXP * 4 + tail) ksplit = 8;
    else if (ws_size >= (size_t)4 * TOKENS * NEXP * 4 + tail) ksplit = 4;
    else                                                      ksplit = 2;

    float* part  = (float*)d_ws;
    float* p_imp = part + (size_t)ksplit * TOKENS * NEXP;
    float* p_cnt = p_imp + 256 * NEXP;

    const int grid = (TOKENS / 256) * ksplit;
    if (ksplit == 8)      logits_kernel< DM/8 ><<<grid, 256, 0, stream>>>(x, wg, part);
    else if (ksplit == 4) logits_kernel< DM/4 ><<<grid, 256, 0, stream>>>(x, wg, part);
    else                  logits_kernel< DM/2 ><<<grid, 256, 0, stream>>>(x, wg, part);

    gate_kernel<<<TOKENS/64, 256, 0, stream>>>(part, out, p_imp, p_cnt, ksplit);
    aux_kernel<<<1, 256, 0, stream>>>(p_imp, p_cnt, out);
}